// Round 9
// baseline (4323.936 us; speedup 1.0000x reference)
//
#include <hip/hip_runtime.h>
#include <hip/hip_bf16.h>
#include <math.h>

#define SLEN 2048
#define DDIM 512
#define BNUM 8
#define MTOT (BNUM * SLEN)   // 16384

typedef float f32x4 __attribute__((ext_vector_type(4)));

// ---------------------------------------------------------------------------
// Device-scope (sc1) 8-byte access helpers. On gfx950 sc0/sc1 form a SCOPE
// field: 00=CU, 01(sc0)=Shader Engine, 10(sc1)=Device, 11=System. Device is
// the narrowest scope that is coherent across CUs on different SEs/XCDs
// (round-8 lesson: sc0 = SE scope silently fails cross-CU). ALL readers and
// writers of the tag buffer use exactly this path (round-3 lesson).
// ---------------------------------------------------------------------------
__device__ __forceinline__ uint2 ld_u64_dev(const uint2* p) {
    uint2 v;
    asm volatile("global_load_dwordx2 %0, %1, off sc1\n\ts_waitcnt vmcnt(0)"
                 : "=v"(v) : "v"(p) : "memory");
    return v;
}
__device__ __forceinline__ void st_u64_dev(uint2* p, uint2 v) {
    asm volatile("global_store_dwordx2 %0, %1, off sc1"
                 :: "v"(p), "v"(v) : "memory");
}

// ---------------------------------------------------------------------------
// Kernel 0: clear tag buffer through the SAME sc1 path the scan uses.
// ---------------------------------------------------------------------------
__global__ __launch_bounds__(512) void clear_tags_kernel(uint2* stateTag)
{
    int i = blockIdx.x * 512 + threadIdx.x;
    uint2 z; z.x = 0u; z.y = 0u;
    st_u64_dev(&stateTag[i], z);
}

// ---------------------------------------------------------------------------
// Kernel A: fused precompute GEMM  O = act(x @ [Wu|Wa|Wc|Wg]^T + bias)
// 128x128 tile, BK=8, 256 threads, 8x8 microtile. Staging via float4 loads
// (round-9: scalar stride-512 loads were 4x under-coalesced).
// ---------------------------------------------------------------------------
__global__ __launch_bounds__(256) void precompute_kernel(
    const float* __restrict__ x,
    const float* __restrict__ Wu, const float* __restrict__ bu,
    const float* __restrict__ Wa, const float* __restrict__ ba,
    const float* __restrict__ Wc, const float* __restrict__ bc,
    const float* __restrict__ Wg, const float* __restrict__ bg,
    float* __restrict__ gbuf, float* __restrict__ cosb,
    float* __restrict__ sinb, float* __restrict__ cdbuf,
    float* __restrict__ ogout)
{
    __shared__ float As[8][132];
    __shared__ float Bs[8][132];

    const int bn = blockIdx.x * 128;      // 0..1791 in steps of 128
    const int bm = blockIdx.y * 128;      // 0..16383

    const float* W; const float* bias; int mode; int dcol;
    if (bn < 512)       { W = Wu; bias = bu; mode = 0; dcol = bn; }
    else if (bn < 768)  { W = Wa; bias = ba; mode = 1; dcol = bn - 512; }
    else if (bn < 1280) { W = Wc; bias = bc; mode = 2; dcol = bn - 768; }
    else                { W = Wg; bias = bg; mode = 3; dcol = bn - 1280; }

    const int tid = threadIdx.x;
    const int tx = tid & 15, ty = tid >> 4;
    const int smm = tid >> 1;             // staging row 0..127
    const int skq = (tid & 1) << 2;       // staging k quad: 0 or 4

    float acc[8][8];
    #pragma unroll
    for (int i = 0; i < 8; ++i)
        #pragma unroll
        for (int j = 0; j < 8; ++j) acc[i][j] = 0.f;

    for (int k0 = 0; k0 < DDIM; k0 += 8) {
        {
            float4 va = *(const float4*)&x[(size_t)(bm + smm) * DDIM + k0 + skq];
            As[skq + 0][smm] = va.x; As[skq + 1][smm] = va.y;
            As[skq + 2][smm] = va.z; As[skq + 3][smm] = va.w;
            float4 vb = *(const float4*)&W[(size_t)(dcol + smm) * DDIM + k0 + skq];
            Bs[skq + 0][smm] = vb.x; Bs[skq + 1][smm] = vb.y;
            Bs[skq + 2][smm] = vb.z; Bs[skq + 3][smm] = vb.w;
        }
        __syncthreads();
        #pragma unroll
        for (int kk = 0; kk < 8; ++kk) {
            float av[8], bv[8];
            *(float4*)&av[0] = *(const float4*)&As[kk][ty * 8];
            *(float4*)&av[4] = *(const float4*)&As[kk][ty * 8 + 4];
            *(float4*)&bv[0] = *(const float4*)&Bs[kk][tx * 8];
            *(float4*)&bv[4] = *(const float4*)&Bs[kk][tx * 8 + 4];
            #pragma unroll
            for (int i = 0; i < 8; ++i)
                #pragma unroll
                for (int j = 0; j < 8; ++j)
                    acc[i][j] = fmaf(av[i], bv[j], acc[i][j]);
        }
        __syncthreads();
    }

    #pragma unroll
    for (int i = 0; i < 8; ++i) {
        int m = bm + ty * 8 + i;
        #pragma unroll
        for (int j = 0; j < 8; ++j) {
            int n = dcol + tx * 8 + j;
            float v = acc[i][j] + bias[n];
            if (mode == 0) {
                gbuf[(size_t)m * 512 + n] = 1.f / (1.f + expf(-v));
            } else if (mode == 1) {
                cosb[(size_t)m * 256 + n] = cosf(v);
                sinb[(size_t)m * 256 + n] = sinf(v);
            } else if (mode == 2) {
                cdbuf[(size_t)m * 512 + n] = tanhf(v);
            } else {
                ogout[(size_t)m * 512 + n] = 1.f / (1.f + expf(-v));
            }
        }
    }
}

// ---------------------------------------------------------------------------
// Kernel B: sequential scan. 64 WGs x 512 threads: b = wg&7, oct = wg>>3
// owns rows [oct*64, oct*64+64). Wave-per-segment: thread (wave w, lane l)
// computes the partial of row oct*64+l over k-segment [w*64, w*64+64).
// Wave w polls EXACTLY the state segment it consumes -> LDS fill is
// wave-local (no barrier); k-reduce = 8 LDS reads + 7 adds + ONE shfl_xor,
// done by wave `oct`, which also rotates/gates/publishes. One
// __syncthreads per step. Cross-WG exchange: generation-tagged double
// buffer (tag = s+1) at device scope (sc1) — rounds 4-7 proven protocol.
// ---------------------------------------------------------------------------
__global__ __launch_bounds__(512, 2) void scan_kernel(
    const float* __restrict__ Wt, const float* __restrict__ bt,
    const float* __restrict__ gbuf, const float* __restrict__ cosb,
    const float* __restrict__ sinb, const float* __restrict__ cdbuf,
    float* __restrict__ states, uint2* stateTag,
    float* __restrict__ finalOut)
{
    const int wg = blockIdx.x;
    const int b = wg & 7, oct = wg >> 3;
    const int tid = threadIdx.x;
    const int w = tid >> 6;          // wave index = k-segment
    const int l = tid & 63;          // lane = local row / element
    const int o = oct * 64 + l;      // row this lane reduces/publishes
    const int e = w * 64 + l;        // state element this lane polls/fills
    const bool isRed = (w == oct);

    __shared__ float st8[8][68];     // state, one padded row per segment
    __shared__ float part[2][8][68]; // partial sums, parity double-buffered

    // ---- register/AGPR-resident weight slice: Wt[o][w*64 .. w*64+64) ----
    const float* wrow = Wt + (size_t)o * DDIM + w * 64;
    f32x4 w0  = *(const f32x4*)(wrow +  0);
    f32x4 w1  = *(const f32x4*)(wrow +  4);
    f32x4 w2  = *(const f32x4*)(wrow +  8);
    f32x4 w3  = *(const f32x4*)(wrow + 12);
    f32x4 w4  = *(const f32x4*)(wrow + 16);
    f32x4 w5  = *(const f32x4*)(wrow + 20);
    f32x4 w6  = *(const f32x4*)(wrow + 24);
    f32x4 w7  = *(const f32x4*)(wrow + 28);
    f32x4 w8  = *(const f32x4*)(wrow + 32);
    f32x4 w9  = *(const f32x4*)(wrow + 36);
    f32x4 w10 = *(const f32x4*)(wrow + 40);
    f32x4 w11 = *(const f32x4*)(wrow + 44);
    f32x4 w12 = *(const f32x4*)(wrow + 48);
    f32x4 w13 = *(const f32x4*)(wrow + 52);
    f32x4 w14 = *(const f32x4*)(wrow + 56);
    f32x4 w15 = *(const f32x4*)(wrow + 60);
    asm volatile("" : "+v"(w0), "+v"(w1), "+v"(w2),  "+v"(w3),
                      "+v"(w4), "+v"(w5), "+v"(w6),  "+v"(w7),
                      "+v"(w8), "+v"(w9), "+v"(w10), "+v"(w11),
                      "+v"(w12), "+v"(w13), "+v"(w14), "+v"(w15));

    const float btv = bt[o];

    const float* pg  = gbuf  + (size_t)b * SLEN * 512;
    const float* pcd = cdbuf + (size_t)b * SLEN * 512;
    const float* pc  = cosb  + (size_t)b * SLEN * 256;
    const float* psn = sinb  + (size_t)b * SLEN * 256;
    float* stb = states + (size_t)b * SLEN * 512;

    // init S_0 = 0 (each wave its own segment; wave-local ordering)
    st8[w][l] = 0.f;

    // gate prologue (reduce wave only)
    float gN = 0.f, cdN = 0.f, cN = 0.f, snN = 0.f;
    if (isRed) {
        gN  = pg [o];
        cdN = pcd[o];
        cN  = pc [o >> 1];
        snN = psn[o >> 1];
    }

    for (int s = 0; s < SLEN; ++s) {
        // ---- partial over segment w (broadcast LDS reads, weights on-chip) --
        float p0 = 0.f, p1 = 0.f, p2 = 0.f, p3 = 0.f;
        const float* st = &st8[w][0];
        {
            f32x4 sv;
            #define MACV(WV, OFF) \
                sv = *(const f32x4*)(st + OFF); \
                p0 = fmaf(WV.x, sv.x, p0); \
                p1 = fmaf(WV.y, sv.y, p1); \
                p2 = fmaf(WV.z, sv.z, p2); \
                p3 = fmaf(WV.w, sv.w, p3);
            MACV(w0,  0)  MACV(w1,  4)  MACV(w2,  8)  MACV(w3,  12)
            MACV(w4,  16) MACV(w5,  20) MACV(w6,  24) MACV(w7,  28)
            MACV(w8,  32) MACV(w9,  36) MACV(w10, 40) MACV(w11, 44)
            MACV(w12, 48) MACV(w13, 52) MACV(w14, 56) MACV(w15, 60)
            #undef MACV
        }
        part[s & 1][w][l] = (p0 + p1) + (p2 + p3);
        __syncthreads();   // partials for step s ready

        if (isRed) {
            // ---- k-reduce, rotate, gate, publish (tag store FIRST) ----
            float t = btv;
            #pragma unroll
            for (int p = 0; p < 8; ++p) t += part[s & 1][p][l];
            float tp = __shfl_xor(t, 1);
            float rot = (l & 1) ? fmaf(tp, snN, t * cN)
                                : fmaf(t, cN, -(tp * snN));
            float nxt = fmaf(gN, rot, (1.f - gN) * cdN);
            if (s + 1 < SLEN) {   // tag SLEN is never polled
                uint2 u; u.x = __float_as_uint(nxt); u.y = (unsigned)(s + 1);
                st_u64_dev(&stateTag[((size_t)((s + 1) & 1) * BNUM + b) * 512 + o], u);
            }
            stb[(size_t)s * 512 + o] = nxt;          // for emit kernel
            st8[oct][l] = nxt;                       // own segment, next step
            if (s == SLEN - 1) finalOut[b * 512 + o] = nxt;
            int sp1 = (s + 1) & (SLEN - 1);          // wrap harmlessly at end
            gN  = pg [(size_t)sp1 * 512 + o];
            cdN = pcd[(size_t)sp1 * 512 + o];
            cN  = pc [(size_t)sp1 * 256 + (o >> 1)];
            snN = psn[(size_t)sp1 * 256 + (o >> 1)];
        } else if (s + 1 < SLEN) {
            // ---- poll own segment for step s+1, fill LDS (wave-local) ----
            const uint2* pp = &stateTag[((size_t)((s + 1) & 1) * BNUM + b) * 512 + e];
            uint2 u; int guard = 0;
            do { u = ld_u64_dev(pp); }
            while (u.y != (unsigned)(s + 1) && ++guard < (1 << 16));
            st8[w][l] = __uint_as_float(u.x);
        }
        // No second barrier: st8[w] is wave-w-private (program-order ds
        // dependency), and part[] parity is protected by the next barrier:
        // a wave can only reach its parity-p overwrite after the reducer
        // (which read parity p) passed the intervening __syncthreads.
    }
}

// ---------------------------------------------------------------------------
// Kernel C: emitted = og * (states @ Wo^T + bo). og staged in d_out by A.
// Same float4-staging GEMM as kernel A.
// ---------------------------------------------------------------------------
__global__ __launch_bounds__(256) void emit_kernel(
    const float* __restrict__ states, const float* __restrict__ Wo,
    const float* __restrict__ bo, float* __restrict__ out)
{
    __shared__ float As[8][132];
    __shared__ float Bs[8][132];

    const int bn = blockIdx.x * 128;
    const int bm = blockIdx.y * 128;
    const int tid = threadIdx.x;
    const int tx = tid & 15, ty = tid >> 4;
    const int smm = tid >> 1;
    const int skq = (tid & 1) << 2;

    float acc[8][8];
    #pragma unroll
    for (int i = 0; i < 8; ++i)
        #pragma unroll
        for (int j = 0; j < 8; ++j) acc[i][j] = 0.f;

    for (int k0 = 0; k0 < DDIM; k0 += 8) {
        {
            float4 va = *(const float4*)&states[(size_t)(bm + smm) * DDIM + k0 + skq];
            As[skq + 0][smm] = va.x; As[skq + 1][smm] = va.y;
            As[skq + 2][smm] = va.z; As[skq + 3][smm] = va.w;
            float4 vb = *(const float4*)&Wo[(size_t)(bn + smm) * DDIM + k0 + skq];
            Bs[skq + 0][smm] = vb.x; Bs[skq + 1][smm] = vb.y;
            Bs[skq + 2][smm] = vb.z; Bs[skq + 3][smm] = vb.w;
        }
        __syncthreads();
        #pragma unroll
        for (int kk = 0; kk < 8; ++kk) {
            float av[8], bv[8];
            *(float4*)&av[0] = *(const float4*)&As[kk][ty * 8];
            *(float4*)&av[4] = *(const float4*)&As[kk][ty * 8 + 4];
            *(float4*)&bv[0] = *(const float4*)&Bs[kk][tx * 8];
            *(float4*)&bv[4] = *(const float4*)&Bs[kk][tx * 8 + 4];
            #pragma unroll
            for (int i = 0; i < 8; ++i)
                #pragma unroll
                for (int j = 0; j < 8; ++j)
                    acc[i][j] = fmaf(av[i], bv[j], acc[i][j]);
        }
        __syncthreads();
    }

    #pragma unroll
    for (int i = 0; i < 8; ++i) {
        int m = bm + ty * 8 + i;
        #pragma unroll
        for (int j = 0; j < 8; ++j) {
            int n = bn + tx * 8 + j;
            size_t idx = (size_t)m * 512 + n;
            float og = out[idx];
            out[idx] = og * (acc[i][j] + bo[n]);
        }
    }
}

// ---------------------------------------------------------------------------
extern "C" void kernel_launch(void* const* d_in, const int* in_sizes, int n_in,
                              void* d_out, int out_size, void* d_ws, size_t ws_size,
                              hipStream_t stream)
{
    const float* x  = (const float*)d_in[0];
    const float* Wu = (const float*)d_in[1];
    const float* bu = (const float*)d_in[2];
    const float* Wt = (const float*)d_in[3];
    const float* bt = (const float*)d_in[4];
    const float* Wa = (const float*)d_in[5];
    const float* ba = (const float*)d_in[6];
    const float* Wc = (const float*)d_in[7];
    const float* bc = (const float*)d_in[8];
    const float* Wg = (const float*)d_in[9];
    const float* bg = (const float*)d_in[10];
    const float* Wo = (const float*)d_in[11];
    const float* bo = (const float*)d_in[12];
    float* out = (float*)d_out;

    // workspace layout (floats)
    float* wsf    = (float*)d_ws;
    float* gbuf   = wsf;                               // 16384*512
    float* cosb   = gbuf   + (size_t)MTOT * 512;       // 16384*256
    float* sinb   = cosb   + (size_t)MTOT * 256;       // 16384*256
    float* cdbuf  = sinb   + (size_t)MTOT * 256;       // 16384*512
    float* states = cdbuf  + (size_t)MTOT * 512;       // 16384*512
    uint2* stateTag = (uint2*)(states + (size_t)MTOT * 512); // 2*8*512 uint2

    // clear tags through the sc1 path (same path the scan uses).
    clear_tags_kernel<<<16, 512, 0, stream>>>(stateTag);

    precompute_kernel<<<dim3(14, 128), 256, 0, stream>>>(
        x, Wu, bu, Wa, ba, Wc, bc, Wg, bg,
        gbuf, cosb, sinb, cdbuf, out /* og staged in emitted region */);

    scan_kernel<<<64, 512, 0, stream>>>(
        Wt, bt, gbuf, cosb, sinb, cdbuf,
        states, stateTag, out + (size_t)MTOT * 512);

    emit_kernel<<<dim3(4, 128), 256, 0, stream>>>(states, Wo, bo, out);
}

// Round 10
// 3253.949 us; speedup vs baseline: 1.3288x; 1.3288x over previous
//
#include <hip/hip_runtime.h>
#include <hip/hip_bf16.h>
#include <math.h>

#define SLEN 2048
#define DDIM 512
#define BNUM 8
#define MTOT (BNUM * SLEN)   // 16384

typedef float f32x4 __attribute__((ext_vector_type(4)));
typedef short s16x8 __attribute__((ext_vector_type(8)));   // 8 bf16 (4 VGPRs)

// fp32 -> bf16 (RNE) as raw ushort
__device__ __forceinline__ unsigned short f2bf(float f) {
    unsigned u = __float_as_uint(f);
    u += 0x7FFFu + ((u >> 16) & 1u);
    return (unsigned short)(u >> 16);
}

// ---------------------------------------------------------------------------
// Device-scope (sc1) 8-byte access helpers. On gfx950 sc0/sc1 form a SCOPE
// field; sc1 = device scope, the narrowest scope coherent across CUs on
// different SEs/XCDs (round-8 lesson: sc0 = SE scope silently fails
// cross-CU). ALL readers and writers of the tag buffer use this one path.
// ---------------------------------------------------------------------------
__device__ __forceinline__ uint2 ld_u64_dev(const uint2* p) {
    uint2 v;
    asm volatile("global_load_dwordx2 %0, %1, off sc1\n\ts_waitcnt vmcnt(0)"
                 : "=v"(v) : "v"(p) : "memory");
    return v;
}
__device__ __forceinline__ void st_u64_dev(uint2* p, uint2 v) {
    asm volatile("global_store_dwordx2 %0, %1, off sc1"
                 :: "v"(p), "v"(v) : "memory");
}

// ---------------------------------------------------------------------------
// Kernel 0: clear tag buffer through the SAME sc1 path the scan uses.
// ---------------------------------------------------------------------------
__global__ __launch_bounds__(512) void clear_tags_kernel(uint2* stateTag)
{
    int i = blockIdx.x * 512 + threadIdx.x;
    uint2 z; z.x = 0u; z.y = 0u;
    st_u64_dev(&stateTag[i], z);
}

// ---------------------------------------------------------------------------
// Kernel A: fused precompute GEMM via bf16 MFMA.
// O = act(x @ [Wu|Wa|Wc|Wg]^T + bias), 128x128 tile, BK=32, 256 thr = 4
// waves (2x2), each wave 4x4 frags of mfma_f32_16x16x32_bf16.
// LDS rows padded to 40 ushorts (80B): 16B-aligned b128 frag reads.
// A-frag lane l: A[row=l&15][k=(l>>4)*8+j]; B-frag identical pattern on W
// (both operands are row-major with K contiguous). C/D: col=lane&15,
// row=(lane>>4)*4+reg [HW-verified mapping].
// ---------------------------------------------------------------------------
__global__ __launch_bounds__(256) void precompute_kernel(
    const float* __restrict__ x,
    const float* __restrict__ Wu, const float* __restrict__ bu,
    const float* __restrict__ Wa, const float* __restrict__ ba,
    const float* __restrict__ Wc, const float* __restrict__ bc,
    const float* __restrict__ Wg, const float* __restrict__ bg,
    float* __restrict__ gbuf, float* __restrict__ cosb,
    float* __restrict__ sinb, float* __restrict__ cdbuf,
    float* __restrict__ ogout)
{
    __shared__ unsigned short As[128 * 40];
    __shared__ unsigned short Bs[128 * 40];

    const int bn = blockIdx.x * 128;      // 0..1791 in steps of 128
    const int bm = blockIdx.y * 128;      // 0..16383

    const float* W; const float* bias; int mode; int dcol;
    if (bn < 512)       { W = Wu; bias = bu; mode = 0; dcol = bn; }
    else if (bn < 768)  { W = Wa; bias = ba; mode = 1; dcol = bn - 512; }
    else if (bn < 1280) { W = Wc; bias = bc; mode = 2; dcol = bn - 768; }
    else                { W = Wg; bias = bg; mode = 3; dcol = bn - 1280; }

    const int tid  = threadIdx.x;
    const int lane = tid & 63, wv = tid >> 6;
    const int wm = wv >> 1, wn = wv & 1;
    const int lr  = lane & 15;
    const int lkb = (lane >> 4) * 8;      // ushort offset of the 8-k group

    f32x4 acc[4][4];
    #pragma unroll
    for (int i = 0; i < 4; ++i)
        #pragma unroll
        for (int j = 0; j < 4; ++j)
            acc[i][j] = (f32x4){0.f, 0.f, 0.f, 0.f};

    const int r = tid >> 1, h = tid & 1;  // staging: row, k-half
    const float* aSrc = x + (size_t)(bm + r) * DDIM + h * 16;
    const float* bSrc = W + (size_t)(dcol + r) * DDIM + h * 16;
    unsigned short* aDst = &As[r * 40 + h * 16];
    unsigned short* bDst = &Bs[r * 40 + h * 16];

    for (int kt = 0; kt < 16; ++kt) {
        {
            float4 fa0 = *(const float4*)(aSrc + 0);
            float4 fa1 = *(const float4*)(aSrc + 4);
            float4 fa2 = *(const float4*)(aSrc + 8);
            float4 fa3 = *(const float4*)(aSrc + 12);
            union { unsigned short u[8]; s16x8 v; } pa0, pa1;
            pa0.u[0]=f2bf(fa0.x); pa0.u[1]=f2bf(fa0.y); pa0.u[2]=f2bf(fa0.z); pa0.u[3]=f2bf(fa0.w);
            pa0.u[4]=f2bf(fa1.x); pa0.u[5]=f2bf(fa1.y); pa0.u[6]=f2bf(fa1.z); pa0.u[7]=f2bf(fa1.w);
            pa1.u[0]=f2bf(fa2.x); pa1.u[1]=f2bf(fa2.y); pa1.u[2]=f2bf(fa2.z); pa1.u[3]=f2bf(fa2.w);
            pa1.u[4]=f2bf(fa3.x); pa1.u[5]=f2bf(fa3.y); pa1.u[6]=f2bf(fa3.z); pa1.u[7]=f2bf(fa3.w);
            *(s16x8*)(aDst + 0) = pa0.v;
            *(s16x8*)(aDst + 8) = pa1.v;

            float4 fb0 = *(const float4*)(bSrc + 0);
            float4 fb1 = *(const float4*)(bSrc + 4);
            float4 fb2 = *(const float4*)(bSrc + 8);
            float4 fb3 = *(const float4*)(bSrc + 12);
            union { unsigned short u[8]; s16x8 v; } pb0, pb1;
            pb0.u[0]=f2bf(fb0.x); pb0.u[1]=f2bf(fb0.y); pb0.u[2]=f2bf(fb0.z); pb0.u[3]=f2bf(fb0.w);
            pb0.u[4]=f2bf(fb1.x); pb0.u[5]=f2bf(fb1.y); pb0.u[6]=f2bf(fb1.z); pb0.u[7]=f2bf(fb1.w);
            pb1.u[0]=f2bf(fb2.x); pb1.u[1]=f2bf(fb2.y); pb1.u[2]=f2bf(fb2.z); pb1.u[3]=f2bf(fb2.w);
            pb1.u[4]=f2bf(fb3.x); pb1.u[5]=f2bf(fb3.y); pb1.u[6]=f2bf(fb3.z); pb1.u[7]=f2bf(fb3.w);
            *(s16x8*)(bDst + 0) = pb0.v;
            *(s16x8*)(bDst + 8) = pb1.v;

            aSrc += 32; bSrc += 32;
        }
        __syncthreads();

        s16x8 af[4], bf[4];
        #pragma unroll
        for (int i = 0; i < 4; ++i)
            af[i] = *(const s16x8*)&As[(wm * 64 + i * 16 + lr) * 40 + lkb];
        #pragma unroll
        for (int j = 0; j < 4; ++j)
            bf[j] = *(const s16x8*)&Bs[(wn * 64 + j * 16 + lr) * 40 + lkb];
        #pragma unroll
        for (int i = 0; i < 4; ++i)
            #pragma unroll
            for (int j = 0; j < 4; ++j)
                acc[i][j] = __builtin_amdgcn_mfma_f32_16x16x32_bf16(
                    af[i], bf[j], acc[i][j], 0, 0, 0);
        __syncthreads();
    }

    // ---- epilogue: bias + activation, scalar stores ----
    const int orow = (lane >> 4) * 4;
    #pragma unroll
    for (int i = 0; i < 4; ++i) {
        #pragma unroll
        for (int j = 0; j < 4; ++j) {
            #pragma unroll
            for (int v = 0; v < 4; ++v) {
                int m  = bm + wm * 64 + i * 16 + orow + v;
                int nc = dcol + wn * 64 + j * 16 + lr;
                float val = acc[i][j][v] + bias[nc];
                if (mode == 0) {
                    gbuf[(size_t)m * 512 + nc] = 1.f / (1.f + expf(-val));
                } else if (mode == 1) {
                    cosb[(size_t)m * 256 + nc] = cosf(val);
                    sinb[(size_t)m * 256 + nc] = sinf(val);
                } else if (mode == 2) {
                    cdbuf[(size_t)m * 512 + nc] = tanhf(val);
                } else {
                    ogout[(size_t)m * 512 + nc] = 1.f / (1.f + expf(-val));
                }
            }
        }
    }
}

// ---------------------------------------------------------------------------
// Kernel B: sequential scan — UNCHANGED from round 9 (proven). 64 WGs x 512
// threads: b = wg&7, oct = wg>>3 owns rows [oct*64, oct*64+64). Wave-per-
// segment; sc1 generation-tagged double buffer.
// ---------------------------------------------------------------------------
__global__ __launch_bounds__(512, 2) void scan_kernel(
    const float* __restrict__ Wt, const float* __restrict__ bt,
    const float* __restrict__ gbuf, const float* __restrict__ cosb,
    const float* __restrict__ sinb, const float* __restrict__ cdbuf,
    float* __restrict__ states, uint2* stateTag,
    float* __restrict__ finalOut)
{
    const int wg = blockIdx.x;
    const int b = wg & 7, oct = wg >> 3;
    const int tid = threadIdx.x;
    const int w = tid >> 6;          // wave index = k-segment
    const int l = tid & 63;          // lane = local row / element
    const int o = oct * 64 + l;      // row this lane reduces/publishes
    const int e = w * 64 + l;        // state element this lane polls/fills
    const bool isRed = (w == oct);

    __shared__ float st8[8][68];     // state, one padded row per segment
    __shared__ float part[2][8][68]; // partial sums, parity double-buffered

    const float* wrow = Wt + (size_t)o * DDIM + w * 64;
    f32x4 w0  = *(const f32x4*)(wrow +  0);
    f32x4 w1  = *(const f32x4*)(wrow +  4);
    f32x4 w2  = *(const f32x4*)(wrow +  8);
    f32x4 w3  = *(const f32x4*)(wrow + 12);
    f32x4 w4  = *(const f32x4*)(wrow + 16);
    f32x4 w5  = *(const f32x4*)(wrow + 20);
    f32x4 w6  = *(const f32x4*)(wrow + 24);
    f32x4 w7  = *(const f32x4*)(wrow + 28);
    f32x4 w8  = *(const f32x4*)(wrow + 32);
    f32x4 w9  = *(const f32x4*)(wrow + 36);
    f32x4 w10 = *(const f32x4*)(wrow + 40);
    f32x4 w11 = *(const f32x4*)(wrow + 44);
    f32x4 w12 = *(const f32x4*)(wrow + 48);
    f32x4 w13 = *(const f32x4*)(wrow + 52);
    f32x4 w14 = *(const f32x4*)(wrow + 56);
    f32x4 w15 = *(const f32x4*)(wrow + 60);
    asm volatile("" : "+v"(w0), "+v"(w1), "+v"(w2),  "+v"(w3),
                      "+v"(w4), "+v"(w5), "+v"(w6),  "+v"(w7),
                      "+v"(w8), "+v"(w9), "+v"(w10), "+v"(w11),
                      "+v"(w12), "+v"(w13), "+v"(w14), "+v"(w15));

    const float btv = bt[o];

    const float* pg  = gbuf  + (size_t)b * SLEN * 512;
    const float* pcd = cdbuf + (size_t)b * SLEN * 512;
    const float* pc  = cosb  + (size_t)b * SLEN * 256;
    const float* psn = sinb  + (size_t)b * SLEN * 256;
    float* stb = states + (size_t)b * SLEN * 512;

    st8[w][l] = 0.f;

    float gN = 0.f, cdN = 0.f, cN = 0.f, snN = 0.f;
    if (isRed) {
        gN  = pg [o];
        cdN = pcd[o];
        cN  = pc [o >> 1];
        snN = psn[o >> 1];
    }

    for (int s = 0; s < SLEN; ++s) {
        float p0 = 0.f, p1 = 0.f, p2 = 0.f, p3 = 0.f;
        const float* st = &st8[w][0];
        {
            f32x4 sv;
            #define MACV(WV, OFF) \
                sv = *(const f32x4*)(st + OFF); \
                p0 = fmaf(WV.x, sv.x, p0); \
                p1 = fmaf(WV.y, sv.y, p1); \
                p2 = fmaf(WV.z, sv.z, p2); \
                p3 = fmaf(WV.w, sv.w, p3);
            MACV(w0,  0)  MACV(w1,  4)  MACV(w2,  8)  MACV(w3,  12)
            MACV(w4,  16) MACV(w5,  20) MACV(w6,  24) MACV(w7,  28)
            MACV(w8,  32) MACV(w9,  36) MACV(w10, 40) MACV(w11, 44)
            MACV(w12, 48) MACV(w13, 52) MACV(w14, 56) MACV(w15, 60)
            #undef MACV
        }
        part[s & 1][w][l] = (p0 + p1) + (p2 + p3);
        __syncthreads();   // partials for step s ready

        if (isRed) {
            float t = btv;
            #pragma unroll
            for (int p = 0; p < 8; ++p) t += part[s & 1][p][l];
            float tp = __shfl_xor(t, 1);
            float rot = (l & 1) ? fmaf(tp, snN, t * cN)
                                : fmaf(t, cN, -(tp * snN));
            float nxt = fmaf(gN, rot, (1.f - gN) * cdN);
            if (s + 1 < SLEN) {
                uint2 u; u.x = __float_as_uint(nxt); u.y = (unsigned)(s + 1);
                st_u64_dev(&stateTag[((size_t)((s + 1) & 1) * BNUM + b) * 512 + o], u);
            }
            stb[(size_t)s * 512 + o] = nxt;
            st8[oct][l] = nxt;
            if (s == SLEN - 1) finalOut[b * 512 + o] = nxt;
            int sp1 = (s + 1) & (SLEN - 1);
            gN  = pg [(size_t)sp1 * 512 + o];
            cdN = pcd[(size_t)sp1 * 512 + o];
            cN  = pc [(size_t)sp1 * 256 + (o >> 1)];
            snN = psn[(size_t)sp1 * 256 + (o >> 1)];
        } else if (s + 1 < SLEN) {
            const uint2* pp = &stateTag[((size_t)((s + 1) & 1) * BNUM + b) * 512 + e];
            uint2 u; int guard = 0;
            do { u = ld_u64_dev(pp); }
            while (u.y != (unsigned)(s + 1) && ++guard < (1 << 16));
            st8[w][l] = __uint_as_float(u.x);
        }
    }
}

// ---------------------------------------------------------------------------
// Kernel C: emitted = og * (states @ Wo^T + bo) via bf16 MFMA. og staged in
// d_out by kernel A; read then overwritten.
// ---------------------------------------------------------------------------
__global__ __launch_bounds__(256) void emit_kernel(
    const float* __restrict__ states, const float* __restrict__ Wo,
    const float* __restrict__ bo, float* __restrict__ out)
{
    __shared__ unsigned short As[128 * 40];
    __shared__ unsigned short Bs[128 * 40];

    const int bn = blockIdx.x * 128;
    const int bm = blockIdx.y * 128;

    const int tid  = threadIdx.x;
    const int lane = tid & 63, wv = tid >> 6;
    const int wm = wv >> 1, wn = wv & 1;
    const int lr  = lane & 15;
    const int lkb = (lane >> 4) * 8;

    f32x4 acc[4][4];
    #pragma unroll
    for (int i = 0; i < 4; ++i)
        #pragma unroll
        for (int j = 0; j < 4; ++j)
            acc[i][j] = (f32x4){0.f, 0.f, 0.f, 0.f};

    const int r = tid >> 1, h = tid & 1;
    const float* aSrc = states + (size_t)(bm + r) * DDIM + h * 16;
    const float* bSrc = Wo + (size_t)(bn + r) * DDIM + h * 16;
    unsigned short* aDst = &As[r * 40 + h * 16];
    unsigned short* bDst = &Bs[r * 40 + h * 16];

    for (int kt = 0; kt < 16; ++kt) {
        {
            float4 fa0 = *(const float4*)(aSrc + 0);
            float4 fa1 = *(const float4*)(aSrc + 4);
            float4 fa2 = *(const float4*)(aSrc + 8);
            float4 fa3 = *(const float4*)(aSrc + 12);
            union { unsigned short u[8]; s16x8 v; } pa0, pa1;
            pa0.u[0]=f2bf(fa0.x); pa0.u[1]=f2bf(fa0.y); pa0.u[2]=f2bf(fa0.z); pa0.u[3]=f2bf(fa0.w);
            pa0.u[4]=f2bf(fa1.x); pa0.u[5]=f2bf(fa1.y); pa0.u[6]=f2bf(fa1.z); pa0.u[7]=f2bf(fa1.w);
            pa1.u[0]=f2bf(fa2.x); pa1.u[1]=f2bf(fa2.y); pa1.u[2]=f2bf(fa2.z); pa1.u[3]=f2bf(fa2.w);
            pa1.u[4]=f2bf(fa3.x); pa1.u[5]=f2bf(fa3.y); pa1.u[6]=f2bf(fa3.z); pa1.u[7]=f2bf(fa3.w);
            *(s16x8*)(aDst + 0) = pa0.v;
            *(s16x8*)(aDst + 8) = pa1.v;

            float4 fb0 = *(const float4*)(bSrc + 0);
            float4 fb1 = *(const float4*)(bSrc + 4);
            float4 fb2 = *(const float4*)(bSrc + 8);
            float4 fb3 = *(const float4*)(bSrc + 12);
            union { unsigned short u[8]; s16x8 v; } pb0, pb1;
            pb0.u[0]=f2bf(fb0.x); pb0.u[1]=f2bf(fb0.y); pb0.u[2]=f2bf(fb0.z); pb0.u[3]=f2bf(fb0.w);
            pb0.u[4]=f2bf(fb1.x); pb0.u[5]=f2bf(fb1.y); pb0.u[6]=f2bf(fb1.z); pb0.u[7]=f2bf(fb1.w);
            pb1.u[0]=f2bf(fb2.x); pb1.u[1]=f2bf(fb2.y); pb1.u[2]=f2bf(fb2.z); pb1.u[3]=f2bf(fb2.w);
            pb1.u[4]=f2bf(fb3.x); pb1.u[5]=f2bf(fb3.y); pb1.u[6]=f2bf(fb3.z); pb1.u[7]=f2bf(fb3.w);
            *(s16x8*)(bDst + 0) = pb0.v;
            *(s16x8*)(bDst + 8) = pb1.v;

            aSrc += 32; bSrc += 32;
        }
        __syncthreads();

        s16x8 af[4], bf[4];
        #pragma unroll
        for (int i = 0; i < 4; ++i)
            af[i] = *(const s16x8*)&As[(wm * 64 + i * 16 + lr) * 40 + lkb];
        #pragma unroll
        for (int j = 0; j < 4; ++j)
            bf[j] = *(const s16x8*)&Bs[(wn * 64 + j * 16 + lr) * 40 + lkb];
        #pragma unroll
        for (int i = 0; i < 4; ++i)
            #pragma unroll
            for (int j = 0; j < 4; ++j)
                acc[i][j] = __builtin_amdgcn_mfma_f32_16x16x32_bf16(
                    af[i], bf[j], acc[i][j], 0, 0, 0);
        __syncthreads();
    }

    const int orow = (lane >> 4) * 4;
    #pragma unroll
    for (int i = 0; i < 4; ++i) {
        #pragma unroll
        for (int j = 0; j < 4; ++j) {
            #pragma unroll
            for (int v = 0; v < 4; ++v) {
                int m = bm + wm * 64 + i * 16 + orow + v;
                int n = bn + wn * 64 + j * 16 + lr;
                size_t idx = (size_t)m * 512 + n;
                float og = out[idx];
                out[idx] = og * (acc[i][j][v] + bo[n]);
            }
        }
    }
}

// ---------------------------------------------------------------------------
extern "C" void kernel_launch(void* const* d_in, const int* in_sizes, int n_in,
                              void* d_out, int out_size, void* d_ws, size_t ws_size,
                              hipStream_t stream)
{
    const float* x  = (const float*)d_in[0];
    const float* Wu = (const float*)d_in[1];
    const float* bu = (const float*)d_in[2];
    const float* Wt = (const float*)d_in[3];
    const float* bt = (const float*)d_in[4];
    const float* Wa = (const float*)d_in[5];
    const float* ba = (const float*)d_in[6];
    const float* Wc = (const float*)d_in[7];
    const float* bc = (const float*)d_in[8];
    const float* Wg = (const float*)d_in[9];
    const float* bg = (const float*)d_in[10];
    const float* Wo = (const float*)d_in[11];
    const float* bo = (const float*)d_in[12];
    float* out = (float*)d_out;

    // workspace layout (floats)
    float* wsf    = (float*)d_ws;
    float* gbuf   = wsf;                               // 16384*512
    float* cosb   = gbuf   + (size_t)MTOT * 512;       // 16384*256
    float* sinb   = cosb   + (size_t)MTOT * 256;       // 16384*256
    float* cdbuf  = sinb   + (size_t)MTOT * 256;       // 16384*512
    float* states = cdbuf  + (size_t)MTOT * 512;       // 16384*512
    uint2* stateTag = (uint2*)(states + (size_t)MTOT * 512); // 2*8*512 uint2

    clear_tags_kernel<<<16, 512, 0, stream>>>(stateTag);

    precompute_kernel<<<dim3(14, 128), 256, 0, stream>>>(
        x, Wu, bu, Wa, ba, Wc, bc, Wg, bg,
        gbuf, cosb, sinb, cdbuf, out /* og staged in emitted region */);

    scan_kernel<<<64, 512, 0, stream>>>(
        Wt, bt, gbuf, cosb, sinb, cdbuf,
        states, stateTag, out + (size_t)MTOT * 512);

    emit_kernel<<<dim3(4, 128), 256, 0, stream>>>(states, Wo, bo, out);
}

// Round 11
// 3072.680 us; speedup vs baseline: 1.4072x; 1.0590x over previous
//
#include <hip/hip_runtime.h>
#include <hip/hip_bf16.h>
#include <math.h>

#define SLEN 2048
#define DDIM 512
#define BNUM 8
#define MTOT (BNUM * SLEN)   // 16384

typedef float f32x4 __attribute__((ext_vector_type(4)));
typedef short s16x8 __attribute__((ext_vector_type(8)));   // 8 bf16 (4 VGPRs)

// fp32 -> bf16 (RNE) as raw ushort
__device__ __forceinline__ unsigned short f2bf(float f) {
    unsigned u = __float_as_uint(f);
    u += 0x7FFFu + ((u >> 16) & 1u);
    return (unsigned short)(u >> 16);
}

// ---------------------------------------------------------------------------
// Device-scope (sc1) 8-byte access helpers. On gfx950 sc0/sc1 form a SCOPE
// field; sc1 = device scope, the narrowest scope coherent across CUs on
// different SEs/XCDs (round-8 lesson: sc0 = SE scope silently fails
// cross-CU). ALL readers and writers of the tag buffer use this one path.
// ---------------------------------------------------------------------------
__device__ __forceinline__ uint2 ld_u64_dev(const uint2* p) {
    uint2 v;
    asm volatile("global_load_dwordx2 %0, %1, off sc1\n\ts_waitcnt vmcnt(0)"
                 : "=v"(v) : "v"(p) : "memory");
    return v;
}
__device__ __forceinline__ void st_u64_dev(uint2* p, uint2 v) {
    asm volatile("global_store_dwordx2 %0, %1, off sc1"
                 :: "v"(p), "v"(v) : "memory");
}

// ---------------------------------------------------------------------------
// Kernel 0: clear tag buffer through the SAME sc1 path the scan uses.
// ---------------------------------------------------------------------------
__global__ __launch_bounds__(512) void clear_tags_kernel(uint2* stateTag)
{
    int i = blockIdx.x * 512 + threadIdx.x;
    uint2 z; z.x = 0u; z.y = 0u;
    st_u64_dev(&stateTag[i], z);
}

// ---------------------------------------------------------------------------
// Kernel A: fused precompute GEMM via bf16 MFMA (round-10, proven).
// ---------------------------------------------------------------------------
__global__ __launch_bounds__(256) void precompute_kernel(
    const float* __restrict__ x,
    const float* __restrict__ Wu, const float* __restrict__ bu,
    const float* __restrict__ Wa, const float* __restrict__ ba,
    const float* __restrict__ Wc, const float* __restrict__ bc,
    const float* __restrict__ Wg, const float* __restrict__ bg,
    float* __restrict__ gbuf, float* __restrict__ cosb,
    float* __restrict__ sinb, float* __restrict__ cdbuf,
    float* __restrict__ ogout)
{
    __shared__ unsigned short As[128 * 40];
    __shared__ unsigned short Bs[128 * 40];

    const int bn = blockIdx.x * 128;      // 0..1791 in steps of 128
    const int bm = blockIdx.y * 128;      // 0..16383

    const float* W; const float* bias; int mode; int dcol;
    if (bn < 512)       { W = Wu; bias = bu; mode = 0; dcol = bn; }
    else if (bn < 768)  { W = Wa; bias = ba; mode = 1; dcol = bn - 512; }
    else if (bn < 1280) { W = Wc; bias = bc; mode = 2; dcol = bn - 768; }
    else                { W = Wg; bias = bg; mode = 3; dcol = bn - 1280; }

    const int tid  = threadIdx.x;
    const int lane = tid & 63, wv = tid >> 6;
    const int wm = wv >> 1, wn = wv & 1;
    const int lr  = lane & 15;
    const int lkb = (lane >> 4) * 8;      // ushort offset of the 8-k group

    f32x4 acc[4][4];
    #pragma unroll
    for (int i = 0; i < 4; ++i)
        #pragma unroll
        for (int j = 0; j < 4; ++j)
            acc[i][j] = (f32x4){0.f, 0.f, 0.f, 0.f};

    const int r = tid >> 1, h = tid & 1;  // staging: row, k-half
    const float* aSrc = x + (size_t)(bm + r) * DDIM + h * 16;
    const float* bSrc = W + (size_t)(dcol + r) * DDIM + h * 16;
    unsigned short* aDst = &As[r * 40 + h * 16];
    unsigned short* bDst = &Bs[r * 40 + h * 16];

    for (int kt = 0; kt < 16; ++kt) {
        {
            float4 fa0 = *(const float4*)(aSrc + 0);
            float4 fa1 = *(const float4*)(aSrc + 4);
            float4 fa2 = *(const float4*)(aSrc + 8);
            float4 fa3 = *(const float4*)(aSrc + 12);
            union { unsigned short u[8]; s16x8 v; } pa0, pa1;
            pa0.u[0]=f2bf(fa0.x); pa0.u[1]=f2bf(fa0.y); pa0.u[2]=f2bf(fa0.z); pa0.u[3]=f2bf(fa0.w);
            pa0.u[4]=f2bf(fa1.x); pa0.u[5]=f2bf(fa1.y); pa0.u[6]=f2bf(fa1.z); pa0.u[7]=f2bf(fa1.w);
            pa1.u[0]=f2bf(fa2.x); pa1.u[1]=f2bf(fa2.y); pa1.u[2]=f2bf(fa2.z); pa1.u[3]=f2bf(fa2.w);
            pa1.u[4]=f2bf(fa3.x); pa1.u[5]=f2bf(fa3.y); pa1.u[6]=f2bf(fa3.z); pa1.u[7]=f2bf(fa3.w);
            *(s16x8*)(aDst + 0) = pa0.v;
            *(s16x8*)(aDst + 8) = pa1.v;

            float4 fb0 = *(const float4*)(bSrc + 0);
            float4 fb1 = *(const float4*)(bSrc + 4);
            float4 fb2 = *(const float4*)(bSrc + 8);
            float4 fb3 = *(const float4*)(bSrc + 12);
            union { unsigned short u[8]; s16x8 v; } pb0, pb1;
            pb0.u[0]=f2bf(fb0.x); pb0.u[1]=f2bf(fb0.y); pb0.u[2]=f2bf(fb0.z); pb0.u[3]=f2bf(fb0.w);
            pb0.u[4]=f2bf(fb1.x); pb0.u[5]=f2bf(fb1.y); pb0.u[6]=f2bf(fb1.z); pb0.u[7]=f2bf(fb1.w);
            pb1.u[0]=f2bf(fb2.x); pb1.u[1]=f2bf(fb2.y); pb1.u[2]=f2bf(fb2.z); pb1.u[3]=f2bf(fb2.w);
            pb1.u[4]=f2bf(fb3.x); pb1.u[5]=f2bf(fb3.y); pb1.u[6]=f2bf(fb3.z); pb1.u[7]=f2bf(fb3.w);
            *(s16x8*)(bDst + 0) = pb0.v;
            *(s16x8*)(bDst + 8) = pb1.v;

            aSrc += 32; bSrc += 32;
        }
        __syncthreads();

        s16x8 af[4], bf[4];
        #pragma unroll
        for (int i = 0; i < 4; ++i)
            af[i] = *(const s16x8*)&As[(wm * 64 + i * 16 + lr) * 40 + lkb];
        #pragma unroll
        for (int j = 0; j < 4; ++j)
            bf[j] = *(const s16x8*)&Bs[(wn * 64 + j * 16 + lr) * 40 + lkb];
        #pragma unroll
        for (int i = 0; i < 4; ++i)
            #pragma unroll
            for (int j = 0; j < 4; ++j)
                acc[i][j] = __builtin_amdgcn_mfma_f32_16x16x32_bf16(
                    af[i], bf[j], acc[i][j], 0, 0, 0);
        __syncthreads();
    }

    // ---- epilogue: bias + activation ----
    const int orow = (lane >> 4) * 4;
    #pragma unroll
    for (int i = 0; i < 4; ++i) {
        #pragma unroll
        for (int j = 0; j < 4; ++j) {
            #pragma unroll
            for (int v = 0; v < 4; ++v) {
                int m  = bm + wm * 64 + i * 16 + orow + v;
                int nc = dcol + wn * 64 + j * 16 + lr;
                float val = acc[i][j][v] + bias[nc];
                if (mode == 0) {
                    gbuf[(size_t)m * 512 + nc] = 1.f / (1.f + expf(-val));
                } else if (mode == 1) {
                    cosb[(size_t)m * 256 + nc] = cosf(val);
                    sinb[(size_t)m * 256 + nc] = sinf(val);
                } else if (mode == 2) {
                    cdbuf[(size_t)m * 512 + nc] = tanhf(val);
                } else {
                    ogout[(size_t)m * 512 + nc] = 1.f / (1.f + expf(-val));
                }
            }
        }
    }
}

// ---------------------------------------------------------------------------
// Kernel B: sequential scan, fused one-barrier layout. 64 WGs x 512 thr:
// b = wg&7, oct = wg>>3 owns rows [oct*64, oct*64+64). Lane (wave w, lane
// l): row o = oct*64 + w*8 + (l>>3), k-segment (l&7)*64 -> 64 fp32 weights
// in VGPR/AGPR. k-reduce: shfl_xor(1,2,4) within the 8-lane group; rotation
// partner via shfl_xor(8). Lanes with (l&7)==0 rotate/gate/publish their
// row (8 per wave -> publish issue spread across all 8 waves). Wave w != oct
// polls state segment w. State LDS parity double-buffered stt[2][8][68]:
// computes read parity s while fills write parity s+1 -> ONE __syncthreads
// per step. Cross-WG exchange: sc1 generation-tagged double buffer (tag =
// s+1), rounds 4-10 proven. Backpressure: publishing s+3 (same parity slot
// as s+1) requires all peers published s+2, which requires they fully
// consumed s+1.
// ---------------------------------------------------------------------------
__global__ __launch_bounds__(512, 2) void scan_kernel(
    const float* __restrict__ Wt, const float* __restrict__ bt,
    const float* __restrict__ gbuf, const float* __restrict__ cosb,
    const float* __restrict__ sinb, const float* __restrict__ cdbuf,
    float* __restrict__ states, uint2* stateTag,
    float* __restrict__ finalOut)
{
    const int wg = blockIdx.x;
    const int b = wg & 7, oct = wg >> 3;
    const int tid = threadIdx.x;
    const int w = tid >> 6;          // wave index
    const int l = tid & 63;
    const int kseg = l & 7;          // k-segment of this lane's 64-wide slice
    const int rl = l >> 3;           // row within the wave's 8-row group
    const int o = oct * 64 + w * 8 + rl;   // row this lane computes
    const int e = w * 64 + l;        // state element wave w polls (w != oct)
    const bool isPub = (kseg == 0);

    __shared__ float stt[2][8][68];  // [parity][segment][element], padded

    // ---- register/AGPR-resident weight slice: Wt[o][kseg*64 .. +64) ----
    const float* wrow = Wt + (size_t)o * DDIM + kseg * 64;
    f32x4 w0  = *(const f32x4*)(wrow +  0);
    f32x4 w1  = *(const f32x4*)(wrow +  4);
    f32x4 w2  = *(const f32x4*)(wrow +  8);
    f32x4 w3  = *(const f32x4*)(wrow + 12);
    f32x4 w4  = *(const f32x4*)(wrow + 16);
    f32x4 w5  = *(const f32x4*)(wrow + 20);
    f32x4 w6  = *(const f32x4*)(wrow + 24);
    f32x4 w7  = *(const f32x4*)(wrow + 28);
    f32x4 w8  = *(const f32x4*)(wrow + 32);
    f32x4 w9  = *(const f32x4*)(wrow + 36);
    f32x4 w10 = *(const f32x4*)(wrow + 40);
    f32x4 w11 = *(const f32x4*)(wrow + 44);
    f32x4 w12 = *(const f32x4*)(wrow + 48);
    f32x4 w13 = *(const f32x4*)(wrow + 52);
    f32x4 w14 = *(const f32x4*)(wrow + 56);
    f32x4 w15 = *(const f32x4*)(wrow + 60);
    asm volatile("" : "+v"(w0), "+v"(w1), "+v"(w2),  "+v"(w3),
                      "+v"(w4), "+v"(w5), "+v"(w6),  "+v"(w7),
                      "+v"(w8), "+v"(w9), "+v"(w10), "+v"(w11),
                      "+v"(w12), "+v"(w13), "+v"(w14), "+v"(w15));

    const float btv = bt[o];

    const float* pg  = gbuf  + (size_t)b * SLEN * 512;
    const float* pcd = cdbuf + (size_t)b * SLEN * 512;
    const float* pc  = cosb  + (size_t)b * SLEN * 256;
    const float* psn = sinb  + (size_t)b * SLEN * 256;
    float* stb = states + (size_t)b * SLEN * 512;

    // init S_0 = 0 in parity 0 (each wave writes its segment row)
    stt[0][w][l] = 0.f;

    // gate prologue (publishing lanes only; one row each)
    float gN = 0.f, cdN = 0.f, cN = 0.f, snN = 0.f;
    if (isPub) {
        gN  = pg [o];
        cdN = pcd[o];
        cN  = pc [o >> 1];
        snN = psn[o >> 1];
    }
    __syncthreads();

    for (int s = 0; s < SLEN; ++s) {
        const int par = s & 1;

        // ---- partial over k-segment (64 MACs; LDS broadcast + 32-bank
        //      conflict-free: 8 distinct b128 addrs span all banks) ----
        float p0 = 0.f, p1 = 0.f, p2 = 0.f, p3 = 0.f;
        const float* st = &stt[par][kseg][0];
        {
            f32x4 sv;
            #define MACV(WV, OFF) \
                sv = *(const f32x4*)(st + OFF); \
                p0 = fmaf(WV.x, sv.x, p0); \
                p1 = fmaf(WV.y, sv.y, p1); \
                p2 = fmaf(WV.z, sv.z, p2); \
                p3 = fmaf(WV.w, sv.w, p3);
            MACV(w0,  0)  MACV(w1,  4)  MACV(w2,  8)  MACV(w3,  12)
            MACV(w4,  16) MACV(w5,  20) MACV(w6,  24) MACV(w7,  28)
            MACV(w8,  32) MACV(w9,  36) MACV(w10, 40) MACV(w11, 44)
            MACV(w12, 48) MACV(w13, 52) MACV(w14, 56) MACV(w15, 60)
            #undef MACV
        }
        float t = (p0 + p1) + (p2 + p3);
        t += __shfl_xor(t, 1);
        t += __shfl_xor(t, 2);
        t += __shfl_xor(t, 4);     // all 8 lanes of the group hold the dot
        t += btv;
        float tp = __shfl_xor(t, 8);   // partner row's value (rl ^ 1)

        if (isPub) {
            // ---- rotate, gate, publish row o (tag store FIRST) ----
            float rot = (rl & 1) ? fmaf(tp, snN, t * cN)
                                 : fmaf(t, cN, -(tp * snN));
            float nxt = fmaf(gN, rot, (1.f - gN) * cdN);
            if (s + 1 < SLEN) {   // tag SLEN is never polled
                uint2 u; u.x = __float_as_uint(nxt); u.y = (unsigned)(s + 1);
                st_u64_dev(&stateTag[((size_t)((s + 1) & 1) * BNUM + b) * 512 + o], u);
            }
            stb[(size_t)s * 512 + o] = nxt;            // for emit kernel
            stt[par ^ 1][oct][w * 8 + rl] = nxt;       // own element, next step
            if (s == SLEN - 1) finalOut[b * 512 + o] = nxt;
            int sp1 = (s + 1) & (SLEN - 1);            // wrap harmlessly at end
            gN  = pg [(size_t)sp1 * 512 + o];
            cdN = pcd[(size_t)sp1 * 512 + o];
            cN  = pc [(size_t)sp1 * 256 + (o >> 1)];
            snN = psn[(size_t)sp1 * 256 + (o >> 1)];
        }
        if (w != oct && s + 1 < SLEN) {
            // ---- poll segment w for step s+1, fill other parity ----
            const uint2* pp = &stateTag[((size_t)((s + 1) & 1) * BNUM + b) * 512 + e];
            uint2 u; int guard = 0;
            do { u = ld_u64_dev(pp); }
            while (u.y != (unsigned)(s + 1) && ++guard < (1 << 16));
            stt[par ^ 1][w][l] = __uint_as_float(u.x);
        }
        __syncthreads();   // stt[par^1] complete -> next step's compute
    }
}

// ---------------------------------------------------------------------------
// Kernel C: emitted = og * (states @ Wo^T + bo) via bf16 MFMA (round-10,
// proven). og staged in d_out by kernel A; read then overwritten.
// ---------------------------------------------------------------------------
__global__ __launch_bounds__(256) void emit_kernel(
    const float* __restrict__ states, const float* __restrict__ Wo,
    const float* __restrict__ bo, float* __restrict__ out)
{
    __shared__ unsigned short As[128 * 40];
    __shared__ unsigned short Bs[128 * 40];

    const int bn = blockIdx.x * 128;
    const int bm = blockIdx.y * 128;

    const int tid  = threadIdx.x;
    const int lane = tid & 63, wv = tid >> 6;
    const int wm = wv >> 1, wn = wv & 1;
    const int lr  = lane & 15;
    const int lkb = (lane >> 4) * 8;

    f32x4 acc[4][4];
    #pragma unroll
    for (int i = 0; i < 4; ++i)
        #pragma unroll
        for (int j = 0; j < 4; ++j)
            acc[i][j] = (f32x4){0.f, 0.f, 0.f, 0.f};

    const int r = tid >> 1, h = tid & 1;
    const float* aSrc = states + (size_t)(bm + r) * DDIM + h * 16;
    const float* bSrc = Wo + (size_t)(bn + r) * DDIM + h * 16;
    unsigned short* aDst = &As[r * 40 + h * 16];
    unsigned short* bDst = &Bs[r * 40 + h * 16];

    for (int kt = 0; kt < 16; ++kt) {
        {
            float4 fa0 = *(const float4*)(aSrc + 0);
            float4 fa1 = *(const float4*)(aSrc + 4);
            float4 fa2 = *(const float4*)(aSrc + 8);
            float4 fa3 = *(const float4*)(aSrc + 12);
            union { unsigned short u[8]; s16x8 v; } pa0, pa1;
            pa0.u[0]=f2bf(fa0.x); pa0.u[1]=f2bf(fa0.y); pa0.u[2]=f2bf(fa0.z); pa0.u[3]=f2bf(fa0.w);
            pa0.u[4]=f2bf(fa1.x); pa0.u[5]=f2bf(fa1.y); pa0.u[6]=f2bf(fa1.z); pa0.u[7]=f2bf(fa1.w);
            pa1.u[0]=f2bf(fa2.x); pa1.u[1]=f2bf(fa2.y); pa1.u[2]=f2bf(fa2.z); pa1.u[3]=f2bf(fa2.w);
            pa1.u[4]=f2bf(fa3.x); pa1.u[5]=f2bf(fa3.y); pa1.u[6]=f2bf(fa3.z); pa1.u[7]=f2bf(fa3.w);
            *(s16x8*)(aDst + 0) = pa0.v;
            *(s16x8*)(aDst + 8) = pa1.v;

            float4 fb0 = *(const float4*)(bSrc + 0);
            float4 fb1 = *(const float4*)(bSrc + 4);
            float4 fb2 = *(const float4*)(bSrc + 8);
            float4 fb3 = *(const float4*)(bSrc + 12);
            union { unsigned short u[8]; s16x8 v; } pb0, pb1;
            pb0.u[0]=f2bf(fb0.x); pb0.u[1]=f2bf(fb0.y); pb0.u[2]=f2bf(fb0.z); pb0.u[3]=f2bf(fb0.w);
            pb0.u[4]=f2bf(fb1.x); pb0.u[5]=f2bf(fb1.y); pb0.u[6]=f2bf(fb1.z); pb0.u[7]=f2bf(fb1.w);
            pb1.u[0]=f2bf(fb2.x); pb1.u[1]=f2bf(fb2.y); pb1.u[2]=f2bf(fb2.z); pb1.u[3]=f2bf(fb2.w);
            pb1.u[4]=f2bf(fb3.x); pb1.u[5]=f2bf(fb3.y); pb1.u[6]=f2bf(fb3.z); pb1.u[7]=f2bf(fb3.w);
            *(s16x8*)(bDst + 0) = pb0.v;
            *(s16x8*)(bDst + 8) = pb1.v;

            aSrc += 32; bSrc += 32;
        }
        __syncthreads();

        s16x8 af[4], bf[4];
        #pragma unroll
        for (int i = 0; i < 4; ++i)
            af[i] = *(const s16x8*)&As[(wm * 64 + i * 16 + lr) * 40 + lkb];
        #pragma unroll
        for (int j = 0; j < 4; ++j)
            bf[j] = *(const s16x8*)&Bs[(wn * 64 + j * 16 + lr) * 40 + lkb];
        #pragma unroll
        for (int i = 0; i < 4; ++i)
            #pragma unroll
            for (int j = 0; j < 4; ++j)
                acc[i][j] = __builtin_amdgcn_mfma_f32_16x16x32_bf16(
                    af[i], bf[j], acc[i][j], 0, 0, 0);
        __syncthreads();
    }

    const int orow = (lane >> 4) * 4;
    #pragma unroll
    for (int i = 0; i < 4; ++i) {
        #pragma unroll
        for (int j = 0; j < 4; ++j) {
            #pragma unroll
            for (int v = 0; v < 4; ++v) {
                int m = bm + wm * 64 + i * 16 + orow + v;
                int n = bn + wn * 64 + j * 16 + lr;
                size_t idx = (size_t)m * 512 + n;
                float og = out[idx];
                out[idx] = og * (acc[i][j][v] + bo[n]);
            }
        }
    }
}

// ---------------------------------------------------------------------------
extern "C" void kernel_launch(void* const* d_in, const int* in_sizes, int n_in,
                              void* d_out, int out_size, void* d_ws, size_t ws_size,
                              hipStream_t stream)
{
    const float* x  = (const float*)d_in[0];
    const float* Wu = (const float*)d_in[1];
    const float* bu = (const float*)d_in[2];
    const float* Wt = (const float*)d_in[3];
    const float* bt = (const float*)d_in[4];
    const float* Wa = (const float*)d_in[5];
    const float* ba = (const float*)d_in[6];
    const float* Wc = (const float*)d_in[7];
    const float* bc = (const float*)d_in[8];
    const float* Wg = (const float*)d_in[9];
    const float* bg = (const float*)d_in[10];
    const float* Wo = (const float*)d_in[11];
    const float* bo = (const float*)d_in[12];
    float* out = (float*)d_out;

    // workspace layout (floats)
    float* wsf    = (float*)d_ws;
    float* gbuf   = wsf;                               // 16384*512
    float* cosb   = gbuf   + (size_t)MTOT * 512;       // 16384*256
    float* sinb   = cosb   + (size_t)MTOT * 256;       // 16384*256
    float* cdbuf  = sinb   + (size_t)MTOT * 256;       // 16384*512
    float* states = cdbuf  + (size_t)MTOT * 512;       // 16384*512
    uint2* stateTag = (uint2*)(states + (size_t)MTOT * 512); // 2*8*512 uint2

    clear_tags_kernel<<<16, 512, 0, stream>>>(stateTag);

    precompute_kernel<<<dim3(14, 128), 256, 0, stream>>>(
        x, Wu, bu, Wa, ba, Wc, bc, Wg, bg,
        gbuf, cosb, sinb, cdbuf, out /* og staged in emitted region */);

    scan_kernel<<<64, 512, 0, stream>>>(
        Wt, bt, gbuf, cosb, sinb, cdbuf,
        states, stateTag, out + (size_t)MTOT * 512);

    emit_kernel<<<dim3(4, 128), 256, 0, stream>>>(states, Wo, bo, out);
}